// Round 23
// baseline (392.679 us; speedup 1.0000x reference)
//
#include <hip/hip_runtime.h>

#define NWIN 1024
#define WIN 128
#define DM 128
#define NTOT (NWIN*WIN)

typedef __bf16 bf16;
typedef __bf16 bf16x4 __attribute__((ext_vector_type(4)));
typedef __bf16 bf16x8 __attribute__((ext_vector_type(8)));
typedef float f32x4 __attribute__((ext_vector_type(4)));
typedef float f32x16 __attribute__((ext_vector_type(16)));

#define MFMA16(a,b,c) __builtin_amdgcn_mfma_f32_16x16x32_bf16(a,b,c,0,0,0)
#define MFMA32(a,b,c) __builtin_amdgcn_mfma_f32_32x32x16_bf16(a,b,c,0,0,0)

// scores scale (1/sqrt(16)) * log2(e), folded into Wq/bq so k_attn uses raw exp2
#define QSCALE 0.36067376022224085f

// ---------------- prep kernels ----------------

// grid 512: weights->bf16 (Wq pre-scaled), maps+im init, flag=0
__global__ void k_prep1(const float* __restrict__ inproj, const float* __restrict__ outproj,
                        const float* __restrict__ w1, const float* __restrict__ w2,
                        bf16* __restrict__ whi,
                        int* __restrict__ mq, int* __restrict__ mkv, int* __restrict__ im,
                        int* __restrict__ flag) {
    int i = blockIdx.x * 256 + threadIdx.x;
    if (i == 0) *flag = 0;
    float v;
    if (i < 49152)       v = inproj[i];
    else if (i < 65536)  v = outproj[i - 49152];
    else if (i < 98304)  v = w1[i - 65536];
    else                 v = w2[i - 98304];
    if (i < 16384) v *= QSCALE;          // Wq rows: fold 0.25*log2(e) into Q
    whi[i] = (bf16)v;
    mq[i] = -1; mkv[i] = -1; im[i] = -1;
}

// grid covers max(n_inds, n_prv, 32768): mask-mode detect + scatter maps + inverse map
__global__ void k_prep2(const int* __restrict__ kpm_i, int* __restrict__ flag,
                        const int* __restrict__ inds, const int* __restrict__ keep, int n,
                        const int* __restrict__ inds_p, const int* __restrict__ keep_p, int np,
                        int* __restrict__ mq, int* __restrict__ mkv, int* __restrict__ im) {
    int j = blockIdx.x * 256 + threadIdx.x;
    if (j < 32768) {
        int v = kpm_i[j];
        if (v != 0 && v != 1) atomicOr(flag, 1);
    }
    if (j < n)  { mq[inds[j]] = keep[j]; im[keep[j]] = inds[j]; }
    if (j < np) mkv[inds_p[j]] = keep_p[j];
}

// grid 512: mask expand only
__global__ void k_prep3(const int* __restrict__ kpm_i, const unsigned char* __restrict__ kpm_b,
                        const int* __restrict__ flag, unsigned char* __restrict__ kmask) {
    int i = blockIdx.x * 256 + threadIdx.x;
    int byte_mode = *flag;
    kmask[i] = byte_mode ? (kpm_b[i] != 0) : (kpm_i[i] != 0);
}

// Plain-bf16 GEMM (one 16-row tile): acc += A @ W^T.
__device__ __forceinline__ void proj1p(const bf16* __restrict__ Xh,
                                       const bf16* __restrict__ WH,
                                       int l15, int g16, f32x4 acc[8]) {
    #pragma unroll
    for (int ks = 0; ks < 4; ks++) {
        bf16x8 ah = *(const bf16x8*)(Xh + l15 * 136 + ks*32 + g16*8);
        #pragma unroll
        for (int tn = 0; tn < 8; tn++) {
            bf16x8 bh = *(const bf16x8*)(WH + (size_t)(16*tn + l15) * DM + ks*32 + g16*8);
            acc[tn] = MFMA16(ah, bh, acc[tn]);
        }
    }
}

// ---------------- QKV projection: merged roles, barrier-free, direct stores ----------------
// role 0 = Q (src+pos). role 1 = V then K (grid_prv gathered once; X += pos_prv).
// KEY INSIGHT (R23): each wave's staging rows (tid>>2 in [16wv,16wv+16)) == its GEMM
// rows, so the input tile is wave-local; the only cross-wave use was the OUTPUT
// staging buffer. Direct stores from accumulators delete that buffer (LDS 35.8->17.4KB
// -> 8 blocks/CU) and every __syncthreads (waves fully independent).
// Q/K: 2B stores, 16 contiguous cols/lane-group -> 32B segments, L2 write-merges.
// Vt: packed bf16x4 (4 keys) per lane. Math bit-identical to R22.
// NO min-blocks hint (R16/R17/R20: any min-waves request spills).
__global__ __launch_bounds__(256) void k_qkv(
    const float* __restrict__ src, const float* __restrict__ src_prv,
    const float* __restrict__ pos, const float* __restrict__ pos_prv,
    const bf16* __restrict__ whi,
    const float* __restrict__ bqkv,
    const int* __restrict__ mq, const int* __restrict__ mkv,
    bf16* __restrict__ Qg, bf16* __restrict__ Kg, bf16* __restrict__ Vtg)
{
    const int blk = blockIdx.x;            // 2048 panels, 64 rows each
    const int role = blockIdx.y;           // 0=Q, 1=V+K
    const int rbase = blk * 64;
    const int w = blk >> 1;
    const int kb = (blk & 1) * 64;         // key offset within window (V only)
    const int tid = threadIdx.x;
    const int lane = tid & 63, wv = tid >> 6;
    const int l15 = lane & 15, g16 = lane >> 4;
    __shared__ bf16 X[64*136];             // 17408 B input tile (only LDS)

    const int srow = tid >> 2, sq4 = tid & 3;   // 4 threads per row, 32 cols each (wave-local rows)
    const int p = rbase + srow;

    if (role == 0) {
        // ---- Q: stage gather(src)+pos (wave-local), GEMM, direct store ----
        {
            float4 a[8];
            const int g = mq[p];
            const float4* pr = (const float4*)(pos + (size_t)p * DM + sq4 * 32);
            #pragma unroll
            for (int i = 0; i < 8; i++) a[i] = pr[i];
            if (g >= 0) {
                const float4* sr = (const float4*)(src + (size_t)g * DM + sq4 * 32);
                #pragma unroll
                for (int i = 0; i < 8; i++) {
                    float4 s4 = sr[i];
                    a[i].x += s4.x; a[i].y += s4.y; a[i].z += s4.z; a[i].w += s4.w;
                }
            }
            bf16* xh = X + srow * 136 + sq4 * 32;
            #pragma unroll
            for (int i = 0; i < 8; i++) {
                bf16x4 h = { (bf16)a[i].x, (bf16)a[i].y, (bf16)a[i].z, (bf16)a[i].w };
                *(bf16x4*)(xh + i * 4) = h;
            }
        }
        f32x4 acc[8];
        for (int tn = 0; tn < 8; tn++) acc[tn] = {};
        proj1p(X + 16*wv*136, whi, l15, g16, acc);
        #pragma unroll
        for (int tn = 0; tn < 8; tn++) {
            float bias = bqkv[16*tn + l15] * QSCALE;
            #pragma unroll
            for (int r = 0; r < 4; r++)
                Qg[(size_t)(rbase + 16*wv + 4*g16 + r) * DM + 16*tn + l15] = (bf16)(acc[tn][r] + bias);
        }
    } else {
        // ---- V+K: gather grid_prv once (wave-local); prefetch pos_prv (T14) ----
        const int g = mkv[p];
        float4 pp[8];
        {
            const float4* ppr = (const float4*)(pos_prv + (size_t)p * DM + sq4 * 32);
            #pragma unroll
            for (int i = 0; i < 8; i++) pp[i] = ppr[i];
        }
        {
            bf16* xh = X + srow * 136 + sq4 * 32;
            if (g >= 0) {
                const float4* sr = (const float4*)(src_prv + (size_t)g * DM + sq4 * 32);
                float4 vv[8];
                #pragma unroll
                for (int i = 0; i < 8; i++) vv[i] = sr[i];
                #pragma unroll
                for (int i = 0; i < 8; i++) {
                    bf16x4 h = { (bf16)vv[i].x, (bf16)vv[i].y, (bf16)vv[i].z, (bf16)vv[i].w };
                    *(bf16x4*)(xh + i * 4) = h;
                }
            } else {
                bf16x4 z = { (bf16)0.f, (bf16)0.f, (bf16)0.f, (bf16)0.f };
                #pragma unroll
                for (int i = 0; i < 8; i++) *(bf16x4*)(xh + i * 4) = z;
            }
        }

        // ---- GEMM V; direct Vt store (packed 4 keys/lane) ----
        f32x4 acc[8];
        for (int tn = 0; tn < 8; tn++) acc[tn] = {};
        proj1p(X + 16*wv*136, whi + 256*DM, l15, g16, acc);
        #pragma unroll
        for (int tn = 0; tn < 8; tn++) {
            float bias = bqkv[256 + 16*tn + l15];
            bf16x4 b = { (bf16)(acc[tn][0] + bias), (bf16)(acc[tn][1] + bias),
                         (bf16)(acc[tn][2] + bias), (bf16)(acc[tn][3] + bias) };
            *(bf16x4*)(Vtg + ((size_t)w * 128 + 16*tn + l15) * 128 + kb + 16*wv + 4*g16) = b;
        }

        // ---- X += pos_prv (wave-local rows; prefetched regs) ----
        {
            bf16* xh = X + srow * 136 + sq4 * 32;
            #pragma unroll
            for (int i = 0; i < 8; i++) {
                bf16x4 ch = *(const bf16x4*)(xh + i * 4);
                bf16x4 h = { (bf16)((float)ch.x + pp[i].x), (bf16)((float)ch.y + pp[i].y),
                             (bf16)((float)ch.z + pp[i].z), (bf16)((float)ch.w + pp[i].w) };
                *(bf16x4*)(xh + i * 4) = h;
            }
        }

        // ---- GEMM K; direct store ----
        f32x4 ka[8];
        for (int tn = 0; tn < 8; tn++) ka[tn] = {};
        proj1p(X + 16*wv*136, whi + 128*DM, l15, g16, ka);
        #pragma unroll
        for (int tn = 0; tn < 8; tn++) {
            float bias = bqkv[128 + 16*tn + l15];
            #pragma unroll
            for (int r = 0; r < 4; r++)
                Kg[(size_t)(rbase + 16*wv + 4*g16 + r) * DM + 16*tn + l15] = (bf16)(ka[tn][r] + bias);
        }
    }
}

// ---------------- attention + out_proj -> dense Ob (per window) ----------------
__global__ __launch_bounds__(256) void k_attn(
    const bf16* __restrict__ Qg, const bf16* __restrict__ Kg, const bf16* __restrict__ Vtg,
    const bf16* __restrict__ whi, const float* __restrict__ ob,
    const unsigned char* __restrict__ kmask,
    bf16* __restrict__ Ob)
{
    const int w = blockIdx.x;
    const int tid = threadIdx.x;
    const int lane = tid & 63, wv = tid >> 6;
    const int l15 = lane & 15, g16 = lane >> 4;
    const int l31 = lane & 31, h32 = lane >> 5;
    __shared__ bf16 P[4][32 * 136];
    bf16* myP = &P[wv][0];

    float mval[4];
    #pragma unroll
    for (int kt = 0; kt < 4; kt++) mval[kt] = kmask[w * WIN + 32*kt + l31] ? -1e9f : 0.f;

    const bf16* Qw = Qg + (size_t)w * WIN * DM;
    const bf16* Kw = Kg + (size_t)w * WIN * DM;
    const bf16* Vw = Vtg + (size_t)w * WIN * DM;

    f32x4 oacc[8][2];
    for (int h = 0; h < 8; h++) { oacc[h][0] = {}; oacc[h][1] = {}; }

    #pragma unroll
    for (int h = 0; h < 8; h++) {
        bf16x8 qf = *(const bf16x8*)(Qw + (size_t)(32*wv + l31) * DM + 16*h + h32*8);
        f32x16 s[4];
        #pragma unroll
        for (int kt = 0; kt < 4; kt++) {
            bf16x8 kf = *(const bf16x8*)(Kw + (size_t)(32*kt + l31) * DM + 16*h + h32*8);
            f32x16 z = {};
            s[kt] = MFMA32(qf, kf, z);
        }
        #pragma unroll
        for (int r = 0; r < 16; r++) {
            float s0 = s[0][r] + mval[0];
            float s1 = s[1][r] + mval[1];
            float s2 = s[2][r] + mval[2];
            float s3 = s[3][r] + mval[3];
            float m = fmaxf(fmaxf(s0, s1), fmaxf(s2, s3));
            #pragma unroll
            for (int d = 1; d <= 16; d <<= 1) m = fmaxf(m, __shfl_xor(m, d));
            float e0 = exp2f(s0 - m), e1 = exp2f(s1 - m);
            float e2 = exp2f(s2 - m), e3 = exp2f(s3 - m);
            float sum = e0 + e1 + e2 + e3;
            #pragma unroll
            for (int d = 1; d <= 16; d <<= 1) sum += __shfl_xor(sum, d);
            float inv = __builtin_amdgcn_rcpf(sum);
            int qrow = (r & 3) + 8 * (r >> 2) + 4 * h32;
            myP[qrow * 136 +      l31] = (bf16)(e0 * inv);
            myP[qrow * 136 + 32 + l31] = (bf16)(e1 * inv);
            myP[qrow * 136 + 64 + l31] = (bf16)(e2 * inv);
            myP[qrow * 136 + 96 + l31] = (bf16)(e3 * inv);
        }
        #pragma unroll
        for (int ks = 0; ks < 4; ks++) {
            bf16x8 p0 = *(const bf16x8*)(myP + (l15     ) * 136 + ks*32 + g16*8);
            bf16x8 p1 = *(const bf16x8*)(myP + (16 + l15) * 136 + ks*32 + g16*8);
            bf16x8 vf = *(const bf16x8*)(Vw + (size_t)(16*h + l15) * DM + ks*32 + g16*8);
            oacc[h][0] = MFMA16(p0, vf, oacc[h][0]);
            oacc[h][1] = MFMA16(p1, vf, oacc[h][1]);
        }
    }

    // O -> LDS, out_proj, then dense coalesced Ob write (no scatter)
    #pragma unroll
    for (int h = 0; h < 8; h++) {
        #pragma unroll
        for (int tq = 0; tq < 2; tq++) {
            #pragma unroll
            for (int r = 0; r < 4; r++)
                myP[(16*tq + 4*g16 + r) * 136 + 16*h + l15] = (bf16)oacc[h][tq][r];
        }
    }

    const bf16* Woh = whi + 49152;
    f32x4 oc[2][8];
    for (int tq = 0; tq < 2; tq++)
        for (int tn = 0; tn < 8; tn++)
            oc[tq][tn] = {};
    #pragma unroll
    for (int ks = 0; ks < 4; ks++) {
        bf16x8 a0 = *(const bf16x8*)(myP + (l15     ) * 136 + ks*32 + g16*8);
        bf16x8 a1 = *(const bf16x8*)(myP + (16 + l15) * 136 + ks*32 + g16*8);
        #pragma unroll
        for (int tn = 0; tn < 8; tn++) {
            bf16x8 bh = *(const bf16x8*)(Woh + (size_t)(16*tn + l15) * DM + ks*32 + g16*8);
            oc[0][tn] = MFMA16(a0, bh, oc[0][tn]);
            oc[1][tn] = MFMA16(a1, bh, oc[1][tn]);
        }
    }

    float obv[8];
    #pragma unroll
    for (int tn = 0; tn < 8; tn++) obv[tn] = ob[16*tn + l15];
    #pragma unroll
    for (int tq = 0; tq < 2; tq++) {
        #pragma unroll
        for (int tn = 0; tn < 8; tn++) {
            #pragma unroll
            for (int r = 0; r < 4; r++)
                myP[(16*tq + 4*g16 + r) * 136 + 16*tn + l15] = (bf16)(oc[tq][tn][r] + obv[tn]);
        }
    }
    __syncthreads();
    bf16* Orow = Ob + ((size_t)w * 128 + 32*wv) * DM;
    #pragma unroll
    for (int it = 0; it < 8; it++) {
        int c = it * 64 + lane;
        int row = c >> 4, off = (c & 15) * 8;
        *(bf16x8*)(Orow + (size_t)row * DM + off) = *(const bf16x8*)(myP + row*136 + off);
    }
}

// ---------------- fused residual-gather + LN1 + FFN + residual + LN2 ----------------
// Cooperative LDS weight staging (32KB half-tiles staged once/block); accumulation
// order identical. No launch-bounds cap (R16/R17/R20: min-waves hints spill).
__global__ void k_ffn(
    const float* __restrict__ src, const bf16* __restrict__ Ob, const int* __restrict__ im,
    const bf16* __restrict__ whi,
    const float* __restrict__ g1, const float* __restrict__ b1ln,
    const float* __restrict__ fb1, const float* __restrict__ fb2,
    const float* __restrict__ g2, const float* __restrict__ b2ln,
    float* __restrict__ out)
{
    const int tid = threadIdx.x;
    const int lane = tid & 63, wv = tid >> 6;
    const int l15 = lane & 15, g16 = lane >> 4;
    const int rbase = blockIdx.x * 64 + wv * 16;
    __shared__ bf16 Wb[128 * 136];         // 34816 B staged weight half-tile
    __shared__ bf16 Hd[4][16 * 136];       // 17408 B per-wave H slabs
    bf16* myH = &Hd[wv][0];
    const bf16* W1h = whi + 65536;
    const bf16* W2h = whi + 98304;

    const int srow = tid >> 1, shc = (tid & 1) * 64;   // staging: 2 threads/row, 64 cols each

    // ---- x row (lane owns row rbase+l15): src + Ob[im], LN1 stats in f32 ----
    const int myrow = rbase + l15;
    const int imr = im[myrow];
    float xv[4][8];
    float sum = 0.f, sq = 0.f;
    const float* xrow = src + (size_t)myrow * DM;
    const bf16* orow = Ob + (size_t)(imr < 0 ? 0 : imr) * DM;
    #pragma unroll
    for (int ks = 0; ks < 4; ks++) {
        float4 a = *(const float4*)(xrow + ks*32 + g16*8);
        float4 b = *(const float4*)(xrow + ks*32 + g16*8 + 4);
        xv[ks][0]=a.x; xv[ks][1]=a.y; xv[ks][2]=a.z; xv[ks][3]=a.w;
        xv[ks][4]=b.x; xv[ks][5]=b.y; xv[ks][6]=b.z; xv[ks][7]=b.w;
        if (imr >= 0) {
            bf16x8 ov = *(const bf16x8*)(orow + ks*32 + g16*8);
            #pragma unroll
            for (int j = 0; j < 8; j++) xv[ks][j] = xv[ks][j] + (float)ov[j];
        }
        #pragma unroll
        for (int j = 0; j < 8; j++) { sum += xv[ks][j]; sq += xv[ks][j]*xv[ks][j]; }
    }
    sum += __shfl_xor(sum, 16); sum += __shfl_xor(sum, 32);
    sq  += __shfl_xor(sq, 16);  sq  += __shfl_xor(sq, 32);
    float mean = sum * (1.f/128.f);
    float var  = sq * (1.f/128.f) - mean * mean;
    float rstd = rsqrtf(var + 1e-5f);

    // ---- y = LN1(x) in f32 -> bf16 A-frags ----
    bf16x8 ah[4];
    #pragma unroll
    for (int ks = 0; ks < 4; ks++) {
        #pragma unroll
        for (int j = 0; j < 8; j++) {
            int col = ks*32 + g16*8 + j;
            float y = (xv[ks][j] - mean) * rstd * g1[col] + b1ln[col];
            ah[ks][j] = (bf16)y;
        }
    }

    // ---- FFN in 2 DFF-halves; weights staged in LDS per half ----
    f32x4 o[8];
    #pragma unroll
    for (int tn = 0; tn < 8; tn++) o[tn] = {};
    #pragma unroll
    for (int dh = 0; dh < 2; dh++) {
        // stage W1 half-tile: Wb[r][c] = W1h[(128*dh + r)*128 + c]
        __syncthreads();   // prior Wb reads (GEMM2 of previous dh) complete
        {
            const bf16* Wsrc = W1h + (size_t)(128*dh + srow) * DM + shc;
            bf16* wdst = Wb + srow * 136 + shc;
            #pragma unroll
            for (int i = 0; i < 8; i++)
                *(bf16x8*)(wdst + i*8) = *(const bf16x8*)(Wsrc + i*8);
        }
        __syncthreads();
        // GEMM1 chunk from LDS
        f32x4 h1[8];
        #pragma unroll
        for (int t = 0; t < 8; t++) h1[t] = {};
        #pragma unroll
        for (int ks = 0; ks < 4; ks++) {
            #pragma unroll
            for (int t = 0; t < 8; t++) {
                bf16x8 bh = *(const bf16x8*)(Wb + (16*t + l15) * 136 + ks*32 + g16*8);
                h1[t] = MFMA16(ah[ks], bh, h1[t]);
            }
        }
        #pragma unroll
        for (int t = 0; t < 8; t++) {
            int tn1 = 8*dh + t;
            float bias = fb1[16*tn1 + l15];
            #pragma unroll
            for (int r = 0; r < 4; r++) {
                float v = fmaxf(h1[t][r] + bias, 0.f);
                myH[(4*g16 + r) * 136 + 16*t + l15] = (bf16)v;   // in-wave ordered
            }
        }
        __syncthreads();   // all GEMM1 Wb reads done before overwrite
        // stage W2 half-tile: Wb[r][c] = W2h[r*256 + 128*dh + c]
        {
            const bf16* Wsrc2 = W2h + (size_t)srow * 256 + 128*dh + shc;
            bf16* wdst = Wb + srow * 136 + shc;
            #pragma unroll
            for (int i = 0; i < 8; i++)
                *(bf16x8*)(wdst + i*8) = *(const bf16x8*)(Wsrc2 + i*8);
        }
        __syncthreads();
        // GEMM2 partial from LDS
        #pragma unroll
        for (int ks2 = 0; ks2 < 4; ks2++) {
            bf16x8 a = *(const bf16x8*)(myH + l15 * 136 + ks2*32 + g16*8);
            #pragma unroll
            for (int tn = 0; tn < 8; tn++) {
                bf16x8 bh = *(const bf16x8*)(Wb + (16*tn + l15) * 136 + ks2*32 + g16*8);
                o[tn] = MFMA16(a, bh, o[tn]);
            }
        }
    }

    // ---- residual: recompute x (bit-exact) for C-layout rows, + LN2 ----
    #pragma unroll
    for (int r = 0; r < 4; r++) {
        int rw = 4*g16 + r;
        int row = rbase + rw;
        float bm = __shfl(mean, rw);              // stats live in lanes 0..15
        float br = __shfl(rstd, rw);
        int imr2 = __shfl(imr, rw);
        float tmp[8];
        float s2 = 0.f, q2 = 0.f;
        #pragma unroll
        for (int tn = 0; tn < 8; tn++) {
            int col = 16*tn + l15;
            float xr = src[(size_t)row * DM + col];
            if (imr2 >= 0) xr = xr + (float)Ob[(size_t)imr2 * DM + col];
            float y  = (xr - bm) * br * g1[col] + b1ln[col];
            float v  = o[tn][r] + fb2[col] + y;
            tmp[tn] = v; s2 += v; q2 += v * v;
        }
        #pragma unroll
        for (int d = 1; d <= 8; d <<= 1) { s2 += __shfl_xor(s2, d); q2 += __shfl_xor(q2, d); }
        float mean2 = s2 * (1.f/128.f);
        float var2  = q2 * (1.f/128.f) - mean2 * mean2;
        float rstd2 = rsqrtf(var2 + 1e-5f);
        #pragma unroll
        for (int tn = 0; tn < 8; tn++) {
            int col = 16*tn + l15;
            out[(size_t)row * DM + col] = (tmp[tn] - mean2) * rstd2 * g2[col] + b2ln[col];
        }
    }
}

// ---------------- launcher ----------------
extern "C" void kernel_launch(void* const* d_in, const int* in_sizes, int n_in,
                              void* d_out, int out_size, void* d_ws, size_t ws_size,
                              hipStream_t stream)
{
    const float* src      = (const float*)d_in[0];
    const float* src_prv  = (const float*)d_in[1];
    const float* pos      = (const float*)d_in[2];
    const float* pos_prv  = (const float*)d_in[3];
    const float* inpw     = (const float*)d_in[4];
    const float* inpb     = (const float*)d_in[5];
    const float* outpw    = (const float*)d_in[6];
    const float* outpb    = (const float*)d_in[7];
    const float* l1w      = (const float*)d_in[8];
    const float* l1b      = (const float*)d_in[9];
    const float* l2w      = (const float*)d_in[10];
    const float* l2b      = (const float*)d_in[11];
    const float* ln1g     = (const float*)d_in[12];
    const float* ln1b     = (const float*)d_in[13];
    const float* ln2g     = (const float*)d_in[14];
    const float* ln2b     = (const float*)d_in[15];
    const int* keep       = (const int*)d_in[16];
    const int* keep_p     = (const int*)d_in[17];
    const int* inds       = (const int*)d_in[18];
    const int* inds_p     = (const int*)d_in[19];
    const int n_inds = in_sizes[18], n_prv = in_sizes[19];

    char* wsb = (char*)d_ws;
    bf16* whi  = (bf16*)(wsb);                                  // 262144 B
    int*  mq   = (int*)(wsb + 524288);                          // 524288 B
    int*  mkv  = (int*)(wsb + 1048576);                         // 524288 B
    int*  im   = (int*)(wsb + 1572864);                         // 524288 B
    bf16* Qb   = (bf16*)(wsb + 2097152);                        // 33554432 B
    bf16* Kb   = (bf16*)(wsb + 2097152 + 1u*33554432);          // 33554432 B
    bf16* Vtb  = (bf16*)(wsb + 2097152 + 2u*33554432);          // 33554432 B
    bf16* Ob   = (bf16*)(wsb + 2097152 + 3u*33554432);          // 33554432 B
    unsigned char* kmask = (unsigned char*)(wsb + 2097152 + 4u*33554432);  // 131072 B
    int* mflag = (int*)(wsb + 2097152 + 4u*33554432 + 131072);  // 4 B

    int mmax = n_inds > n_prv ? n_inds : n_prv;
    if (mmax < 32768) mmax = 32768;
    k_prep1<<<512, 256, 0, stream>>>(inpw, outpw, l1w, l2w, whi, mq, mkv, im, mflag);
    k_prep2<<<(mmax + 255) / 256, 256, 0, stream>>>((const int*)d_in[20], mflag,
                                                    inds, keep, n_inds, inds_p, keep_p, n_prv, mq, mkv, im);
    k_prep3<<<512, 256, 0, stream>>>((const int*)d_in[20], (const unsigned char*)d_in[20], mflag, kmask);
    k_qkv<<<dim3(2048, 2), 256, 0, stream>>>(src, src_prv, pos, pos_prv, whi, inpb, mq, mkv, Qb, Kb, Vtb);
    k_attn<<<NWIN, 256, 0, stream>>>(Qb, Kb, Vtb, whi, outpb, kmask, Ob);
    k_ffn<<<NTOT / 64, 256, 0, stream>>>(src, Ob, im, whi, ln1g, ln1b, l1b, l2b, ln2g, ln2b, (float*)d_out);
}

// Round 24
// 375.079 us; speedup vs baseline: 1.0469x; 1.0469x over previous
//
#include <hip/hip_runtime.h>

#define NWIN 1024
#define WIN 128
#define DM 128
#define NTOT (NWIN*WIN)

typedef __bf16 bf16;
typedef __bf16 bf16x4 __attribute__((ext_vector_type(4)));
typedef __bf16 bf16x8 __attribute__((ext_vector_type(8)));
typedef float f32x4 __attribute__((ext_vector_type(4)));
typedef float f32x16 __attribute__((ext_vector_type(16)));

#define MFMA16(a,b,c) __builtin_amdgcn_mfma_f32_16x16x32_bf16(a,b,c,0,0,0)
#define MFMA32(a,b,c) __builtin_amdgcn_mfma_f32_32x32x16_bf16(a,b,c,0,0,0)

// scores scale (1/sqrt(16)) * log2(e), folded into Wq/bq so k_attn uses raw exp2
#define QSCALE 0.36067376022224085f

// ---------------- prep kernels ----------------

// grid 512: weights->bf16 (Wq pre-scaled), maps+im init, flag=0
__global__ void k_prep1(const float* __restrict__ inproj, const float* __restrict__ outproj,
                        const float* __restrict__ w1, const float* __restrict__ w2,
                        bf16* __restrict__ whi,
                        int* __restrict__ mq, int* __restrict__ mkv, int* __restrict__ im,
                        int* __restrict__ flag) {
    int i = blockIdx.x * 256 + threadIdx.x;
    if (i == 0) *flag = 0;
    float v;
    if (i < 49152)       v = inproj[i];
    else if (i < 65536)  v = outproj[i - 49152];
    else if (i < 98304)  v = w1[i - 65536];
    else                 v = w2[i - 98304];
    if (i < 16384) v *= QSCALE;          // Wq rows: fold 0.25*log2(e) into Q
    whi[i] = (bf16)v;
    mq[i] = -1; mkv[i] = -1; im[i] = -1;
}

// grid covers max(n_inds, n_prv, 32768): mask-mode detect + scatter maps + inverse map
__global__ void k_prep2(const int* __restrict__ kpm_i, int* __restrict__ flag,
                        const int* __restrict__ inds, const int* __restrict__ keep, int n,
                        const int* __restrict__ inds_p, const int* __restrict__ keep_p, int np,
                        int* __restrict__ mq, int* __restrict__ mkv, int* __restrict__ im) {
    int j = blockIdx.x * 256 + threadIdx.x;
    if (j < 32768) {
        int v = kpm_i[j];
        if (v != 0 && v != 1) atomicOr(flag, 1);
    }
    if (j < n)  { mq[inds[j]] = keep[j]; im[keep[j]] = inds[j]; }
    if (j < np) mkv[inds_p[j]] = keep_p[j];
}

// grid 512: mask expand only
__global__ void k_prep3(const int* __restrict__ kpm_i, const unsigned char* __restrict__ kpm_b,
                        const int* __restrict__ flag, unsigned char* __restrict__ kmask) {
    int i = blockIdx.x * 256 + threadIdx.x;
    int byte_mode = *flag;
    kmask[i] = byte_mode ? (kpm_b[i] != 0) : (kpm_i[i] != 0);
}

// Plain-bf16 GEMM (one 16-row tile): acc += A @ W^T.
__device__ __forceinline__ void proj1p(const bf16* __restrict__ Xh,
                                       const bf16* __restrict__ WH,
                                       int l15, int g16, f32x4 acc[8]) {
    #pragma unroll
    for (int ks = 0; ks < 4; ks++) {
        bf16x8 ah = *(const bf16x8*)(Xh + l15 * 136 + ks*32 + g16*8);
        #pragma unroll
        for (int tn = 0; tn < 8; tn++) {
            bf16x8 bh = *(const bf16x8*)(WH + (size_t)(16*tn + l15) * DM + ks*32 + g16*8);
            acc[tn] = MFMA16(ah, bh, acc[tn]);
        }
    }
}

// ---------------- QKV projection: merged roles (grid 2048 x 2) ----------------
// role 0 = Q (src+pos). role 1 = V then K: grid_prv gathered ONCE, GEMM V, then
// X += pos_prv (prefetched regs, T14) -> GEMM K. Halves src_prv gather traffic.
// R23 lesson: staged output (LDS bounce) keeps VGPR at 60 (<64 bin); direct stores
// pushed VGPR to 68 -> occupancy cliff. NO min-blocks hint (R16/R17/R20: spills).
__global__ __launch_bounds__(256) void k_qkv(
    const float* __restrict__ src, const float* __restrict__ src_prv,
    const float* __restrict__ pos, const float* __restrict__ pos_prv,
    const bf16* __restrict__ whi,
    const float* __restrict__ bqkv,
    const int* __restrict__ mq, const int* __restrict__ mkv,
    bf16* __restrict__ Qg, bf16* __restrict__ Kg, bf16* __restrict__ Vtg)
{
    const int blk = blockIdx.x;            // 2048 panels, 64 rows each
    const int role = blockIdx.y;           // 0=Q, 1=V+K
    const int rbase = blk * 64;
    const int w = blk >> 1;
    const int kb = (blk & 1) * 64;         // key offset within window (V only)
    const int tid = threadIdx.x;
    const int lane = tid & 63, wv = tid >> 6;
    const int l15 = lane & 15, g16 = lane >> 4;
    __shared__ bf16 X[64*136];             // 17408 B input tile
    __shared__ bf16 St[9216];              // 18432 B output bounce (QK [64][136] / Vt [128][72])

    const int srow = tid >> 2, sq4 = tid & 3;   // 4 threads per row, 32 cols each
    const int p = rbase + srow;

    if (role == 0) {
        // ---- Q: stage gather(src)+pos, GEMM, store ----
        {
            float4 a[8];
            const int g = mq[p];
            const float4* pr = (const float4*)(pos + (size_t)p * DM + sq4 * 32);
            #pragma unroll
            for (int i = 0; i < 8; i++) a[i] = pr[i];
            if (g >= 0) {
                const float4* sr = (const float4*)(src + (size_t)g * DM + sq4 * 32);
                #pragma unroll
                for (int i = 0; i < 8; i++) {
                    float4 s4 = sr[i];
                    a[i].x += s4.x; a[i].y += s4.y; a[i].z += s4.z; a[i].w += s4.w;
                }
            }
            bf16* xh = X + srow * 136 + sq4 * 32;
            #pragma unroll
            for (int i = 0; i < 8; i++) {
                bf16x4 h = { (bf16)a[i].x, (bf16)a[i].y, (bf16)a[i].z, (bf16)a[i].w };
                *(bf16x4*)(xh + i * 4) = h;
            }
        }
        __syncthreads();
        f32x4 acc[8];
        for (int tn = 0; tn < 8; tn++) acc[tn] = {};
        proj1p(X + 16*wv*136, whi, l15, g16, acc);
        #pragma unroll
        for (int tn = 0; tn < 8; tn++) {
            float bias = bqkv[16*tn + l15] * QSCALE;
            #pragma unroll
            for (int r = 0; r < 4; r++)
                St[(16*wv + 4*g16 + r) * 136 + 16*tn + l15] = (bf16)(acc[tn][r] + bias);
        }
        __syncthreads();
        #pragma unroll
        for (int it = 0; it < 4; it++) {
            int c = it * 256 + tid;
            int row = c >> 4, off = (c & 15) * 8;
            *(bf16x8*)(Qg + (size_t)(rbase + row) * DM + off) = *(const bf16x8*)(St + row*136 + off);
        }
    } else {
        // ---- V+K: gather grid_prv ONCE; prefetch pos_prv (T14) ----
        const int g = mkv[p];
        float4 pp[8];
        {
            const float4* ppr = (const float4*)(pos_prv + (size_t)p * DM + sq4 * 32);
            #pragma unroll
            for (int i = 0; i < 8; i++) pp[i] = ppr[i];
        }
        {
            bf16* xh = X + srow * 136 + sq4 * 32;
            if (g >= 0) {
                const float4* sr = (const float4*)(src_prv + (size_t)g * DM + sq4 * 32);
                float4 vv[8];
                #pragma unroll
                for (int i = 0; i < 8; i++) vv[i] = sr[i];
                #pragma unroll
                for (int i = 0; i < 8; i++) {
                    bf16x4 h = { (bf16)vv[i].x, (bf16)vv[i].y, (bf16)vv[i].z, (bf16)vv[i].w };
                    *(bf16x4*)(xh + i * 4) = h;
                }
            } else {
                bf16x4 z = { (bf16)0.f, (bf16)0.f, (bf16)0.f, (bf16)0.f };
                #pragma unroll
                for (int i = 0; i < 8; i++) *(bf16x4*)(xh + i * 4) = z;
            }
        }
        __syncthreads();

        // ---- GEMM V ----
        f32x4 acc[8];
        for (int tn = 0; tn < 8; tn++) acc[tn] = {};
        proj1p(X + 16*wv*136, whi + 256*DM, l15, g16, acc);
        #pragma unroll
        for (int tn = 0; tn < 8; tn++) {
            float bias = bqkv[256 + 16*tn + l15];
            int dim = 16*tn + l15;
            bf16x4 b = { (bf16)(acc[tn][0] + bias), (bf16)(acc[tn][1] + bias),
                         (bf16)(acc[tn][2] + bias), (bf16)(acc[tn][3] + bias) };
            *(bf16x4*)(St + dim * 72 + 16*wv + 4*g16) = b;
        }
        __syncthreads();   // X reads (GEMM V) done; St(Vt) written

        // ---- X += pos_prv (prefetched); store Vt ----
        {
            bf16* xh = X + srow * 136 + sq4 * 32;
            #pragma unroll
            for (int i = 0; i < 8; i++) {
                bf16x4 ch = *(const bf16x4*)(xh + i * 4);
                bf16x4 h = { (bf16)((float)ch.x + pp[i].x), (bf16)((float)ch.y + pp[i].y),
                             (bf16)((float)ch.z + pp[i].z), (bf16)((float)ch.w + pp[i].w) };
                *(bf16x4*)(xh + i * 4) = h;
            }
        }
        #pragma unroll
        for (int it = 0; it < 4; it++) {
            int c = it * 256 + tid;
            int dim = c >> 3, off = (c & 7) * 8;
            *(bf16x8*)(Vtg + ((size_t)w * 128 + dim) * 128 + kb + off) = *(const bf16x8*)(St + dim*72 + off);
        }
        __syncthreads();   // x_k staged; St(Vt) reads done

        // ---- GEMM K ----
        f32x4 ka[8];
        for (int tn = 0; tn < 8; tn++) ka[tn] = {};
        proj1p(X + 16*wv*136, whi + 128*DM, l15, g16, ka);
        #pragma unroll
        for (int tn = 0; tn < 8; tn++) {
            float bias = bqkv[128 + 16*tn + l15];
            #pragma unroll
            for (int r = 0; r < 4; r++)
                St[(16*wv + 4*g16 + r) * 136 + 16*tn + l15] = (bf16)(ka[tn][r] + bias);
        }
        __syncthreads();
        #pragma unroll
        for (int it = 0; it < 4; it++) {
            int c = it * 256 + tid;
            int row = c >> 4, off = (c & 15) * 8;
            *(bf16x8*)(Kg + (size_t)(rbase + row) * DM + off) = *(const bf16x8*)(St + row*136 + off);
        }
    }
}

// ---------------- attention + out_proj -> dense Ob (per window) ----------------
__global__ __launch_bounds__(256) void k_attn(
    const bf16* __restrict__ Qg, const bf16* __restrict__ Kg, const bf16* __restrict__ Vtg,
    const bf16* __restrict__ whi, const float* __restrict__ ob,
    const unsigned char* __restrict__ kmask,
    bf16* __restrict__ Ob)
{
    const int w = blockIdx.x;
    const int tid = threadIdx.x;
    const int lane = tid & 63, wv = tid >> 6;
    const int l15 = lane & 15, g16 = lane >> 4;
    const int l31 = lane & 31, h32 = lane >> 5;
    __shared__ bf16 P[4][32 * 136];
    bf16* myP = &P[wv][0];

    float mval[4];
    #pragma unroll
    for (int kt = 0; kt < 4; kt++) mval[kt] = kmask[w * WIN + 32*kt + l31] ? -1e9f : 0.f;

    const bf16* Qw = Qg + (size_t)w * WIN * DM;
    const bf16* Kw = Kg + (size_t)w * WIN * DM;
    const bf16* Vw = Vtg + (size_t)w * WIN * DM;

    f32x4 oacc[8][2];
    for (int h = 0; h < 8; h++) { oacc[h][0] = {}; oacc[h][1] = {}; }

    #pragma unroll
    for (int h = 0; h < 8; h++) {
        bf16x8 qf = *(const bf16x8*)(Qw + (size_t)(32*wv + l31) * DM + 16*h + h32*8);
        f32x16 s[4];
        #pragma unroll
        for (int kt = 0; kt < 4; kt++) {
            bf16x8 kf = *(const bf16x8*)(Kw + (size_t)(32*kt + l31) * DM + 16*h + h32*8);
            f32x16 z = {};
            s[kt] = MFMA32(qf, kf, z);
        }
        #pragma unroll
        for (int r = 0; r < 16; r++) {
            float s0 = s[0][r] + mval[0];
            float s1 = s[1][r] + mval[1];
            float s2 = s[2][r] + mval[2];
            float s3 = s[3][r] + mval[3];
            float m = fmaxf(fmaxf(s0, s1), fmaxf(s2, s3));
            #pragma unroll
            for (int d = 1; d <= 16; d <<= 1) m = fmaxf(m, __shfl_xor(m, d));
            float e0 = exp2f(s0 - m), e1 = exp2f(s1 - m);
            float e2 = exp2f(s2 - m), e3 = exp2f(s3 - m);
            float sum = e0 + e1 + e2 + e3;
            #pragma unroll
            for (int d = 1; d <= 16; d <<= 1) sum += __shfl_xor(sum, d);
            float inv = __builtin_amdgcn_rcpf(sum);
            int qrow = (r & 3) + 8 * (r >> 2) + 4 * h32;
            myP[qrow * 136 +      l31] = (bf16)(e0 * inv);
            myP[qrow * 136 + 32 + l31] = (bf16)(e1 * inv);
            myP[qrow * 136 + 64 + l31] = (bf16)(e2 * inv);
            myP[qrow * 136 + 96 + l31] = (bf16)(e3 * inv);
        }
        #pragma unroll
        for (int ks = 0; ks < 4; ks++) {
            bf16x8 p0 = *(const bf16x8*)(myP + (l15     ) * 136 + ks*32 + g16*8);
            bf16x8 p1 = *(const bf16x8*)(myP + (16 + l15) * 136 + ks*32 + g16*8);
            bf16x8 vf = *(const bf16x8*)(Vw + (size_t)(16*h + l15) * DM + ks*32 + g16*8);
            oacc[h][0] = MFMA16(p0, vf, oacc[h][0]);
            oacc[h][1] = MFMA16(p1, vf, oacc[h][1]);
        }
    }

    // O -> LDS, out_proj, then dense coalesced Ob write (no scatter)
    #pragma unroll
    for (int h = 0; h < 8; h++) {
        #pragma unroll
        for (int tq = 0; tq < 2; tq++) {
            #pragma unroll
            for (int r = 0; r < 4; r++)
                myP[(16*tq + 4*g16 + r) * 136 + 16*h + l15] = (bf16)oacc[h][tq][r];
        }
    }

    const bf16* Woh = whi + 49152;
    f32x4 oc[2][8];
    for (int tq = 0; tq < 2; tq++)
        for (int tn = 0; tn < 8; tn++)
            oc[tq][tn] = {};
    #pragma unroll
    for (int ks = 0; ks < 4; ks++) {
        bf16x8 a0 = *(const bf16x8*)(myP + (l15     ) * 136 + ks*32 + g16*8);
        bf16x8 a1 = *(const bf16x8*)(myP + (16 + l15) * 136 + ks*32 + g16*8);
        #pragma unroll
        for (int tn = 0; tn < 8; tn++) {
            bf16x8 bh = *(const bf16x8*)(Woh + (size_t)(16*tn + l15) * DM + ks*32 + g16*8);
            oc[0][tn] = MFMA16(a0, bh, oc[0][tn]);
            oc[1][tn] = MFMA16(a1, bh, oc[1][tn]);
        }
    }

    float obv[8];
    #pragma unroll
    for (int tn = 0; tn < 8; tn++) obv[tn] = ob[16*tn + l15];
    #pragma unroll
    for (int tq = 0; tq < 2; tq++) {
        #pragma unroll
        for (int tn = 0; tn < 8; tn++) {
            #pragma unroll
            for (int r = 0; r < 4; r++)
                myP[(16*tq + 4*g16 + r) * 136 + 16*tn + l15] = (bf16)(oc[tq][tn][r] + obv[tn]);
        }
    }
    __syncthreads();
    bf16* Orow = Ob + ((size_t)w * 128 + 32*wv) * DM;
    #pragma unroll
    for (int it = 0; it < 8; it++) {
        int c = it * 64 + lane;
        int row = c >> 4, off = (c & 15) * 8;
        *(bf16x8*)(Orow + (size_t)row * DM + off) = *(const bf16x8*)(myP + row*136 + off);
    }
}

// ---------------- fused residual-gather + LN1 + FFN + residual + LN2 ----------------
// Cooperative LDS weight staging (32KB half-tiles staged once/block); accumulation
// order identical. No launch-bounds cap (R16/R17/R20: min-waves hints spill).
__global__ void k_ffn(
    const float* __restrict__ src, const bf16* __restrict__ Ob, const int* __restrict__ im,
    const bf16* __restrict__ whi,
    const float* __restrict__ g1, const float* __restrict__ b1ln,
    const float* __restrict__ fb1, const float* __restrict__ fb2,
    const float* __restrict__ g2, const float* __restrict__ b2ln,
    float* __restrict__ out)
{
    const int tid = threadIdx.x;
    const int lane = tid & 63, wv = tid >> 6;
    const int l15 = lane & 15, g16 = lane >> 4;
    const int rbase = blockIdx.x * 64 + wv * 16;
    __shared__ bf16 Wb[128 * 136];         // 34816 B staged weight half-tile
    __shared__ bf16 Hd[4][16 * 136];       // 17408 B per-wave H slabs
    bf16* myH = &Hd[wv][0];
    const bf16* W1h = whi + 65536;
    const bf16* W2h = whi + 98304;

    const int srow = tid >> 1, shc = (tid & 1) * 64;   // staging: 2 threads/row, 64 cols each

    // ---- x row (lane owns row rbase+l15): src + Ob[im], LN1 stats in f32 ----
    const int myrow = rbase + l15;
    const int imr = im[myrow];
    float xv[4][8];
    float sum = 0.f, sq = 0.f;
    const float* xrow = src + (size_t)myrow * DM;
    const bf16* orow = Ob + (size_t)(imr < 0 ? 0 : imr) * DM;
    #pragma unroll
    for (int ks = 0; ks < 4; ks++) {
        float4 a = *(const float4*)(xrow + ks*32 + g16*8);
        float4 b = *(const float4*)(xrow + ks*32 + g16*8 + 4);
        xv[ks][0]=a.x; xv[ks][1]=a.y; xv[ks][2]=a.z; xv[ks][3]=a.w;
        xv[ks][4]=b.x; xv[ks][5]=b.y; xv[ks][6]=b.z; xv[ks][7]=b.w;
        if (imr >= 0) {
            bf16x8 ov = *(const bf16x8*)(orow + ks*32 + g16*8);
            #pragma unroll
            for (int j = 0; j < 8; j++) xv[ks][j] = xv[ks][j] + (float)ov[j];
        }
        #pragma unroll
        for (int j = 0; j < 8; j++) { sum += xv[ks][j]; sq += xv[ks][j]*xv[ks][j]; }
    }
    sum += __shfl_xor(sum, 16); sum += __shfl_xor(sum, 32);
    sq  += __shfl_xor(sq, 16);  sq  += __shfl_xor(sq, 32);
    float mean = sum * (1.f/128.f);
    float var  = sq * (1.f/128.f) - mean * mean;
    float rstd = rsqrtf(var + 1e-5f);

    // ---- y = LN1(x) in f32 -> bf16 A-frags ----
    bf16x8 ah[4];
    #pragma unroll
    for (int ks = 0; ks < 4; ks++) {
        #pragma unroll
        for (int j = 0; j < 8; j++) {
            int col = ks*32 + g16*8 + j;
            float y = (xv[ks][j] - mean) * rstd * g1[col] + b1ln[col];
            ah[ks][j] = (bf16)y;
        }
    }

    // ---- FFN in 2 DFF-halves; weights staged in LDS per half ----
    f32x4 o[8];
    #pragma unroll
    for (int tn = 0; tn < 8; tn++) o[tn] = {};
    #pragma unroll
    for (int dh = 0; dh < 2; dh++) {
        // stage W1 half-tile: Wb[r][c] = W1h[(128*dh + r)*128 + c]
        __syncthreads();   // prior Wb reads (GEMM2 of previous dh) complete
        {
            const bf16* Wsrc = W1h + (size_t)(128*dh + srow) * DM + shc;
            bf16* wdst = Wb + srow * 136 + shc;
            #pragma unroll
            for (int i = 0; i < 8; i++)
                *(bf16x8*)(wdst + i*8) = *(const bf16x8*)(Wsrc + i*8);
        }
        __syncthreads();
        // GEMM1 chunk from LDS
        f32x4 h1[8];
        #pragma unroll
        for (int t = 0; t < 8; t++) h1[t] = {};
        #pragma unroll
        for (int ks = 0; ks < 4; ks++) {
            #pragma unroll
            for (int t = 0; t < 8; t++) {
                bf16x8 bh = *(const bf16x8*)(Wb + (16*t + l15) * 136 + ks*32 + g16*8);
                h1[t] = MFMA16(ah[ks], bh, h1[t]);
            }
        }
        #pragma unroll
        for (int t = 0; t < 8; t++) {
            int tn1 = 8*dh + t;
            float bias = fb1[16*tn1 + l15];
            #pragma unroll
            for (int r = 0; r < 4; r++) {
                float v = fmaxf(h1[t][r] + bias, 0.f);
                myH[(4*g16 + r) * 136 + 16*t + l15] = (bf16)v;   // in-wave ordered
            }
        }
        __syncthreads();   // all GEMM1 Wb reads done before overwrite
        // stage W2 half-tile: Wb[r][c] = W2h[r*256 + 128*dh + c]
        {
            const bf16* Wsrc2 = W2h + (size_t)srow * 256 + 128*dh + shc;
            bf16* wdst = Wb + srow * 136 + shc;
            #pragma unroll
            for (int i = 0; i < 8; i++)
                *(bf16x8*)(wdst + i*8) = *(const bf16x8*)(Wsrc2 + i*8);
        }
        __syncthreads();
        // GEMM2 partial from LDS
        #pragma unroll
        for (int ks2 = 0; ks2 < 4; ks2++) {
            bf16x8 a = *(const bf16x8*)(myH + l15 * 136 + ks2*32 + g16*8);
            #pragma unroll
            for (int tn = 0; tn < 8; tn++) {
                bf16x8 bh = *(const bf16x8*)(Wb + (16*tn + l15) * 136 + ks2*32 + g16*8);
                o[tn] = MFMA16(a, bh, o[tn]);
            }
        }
    }

    // ---- residual: recompute x (bit-exact) for C-layout rows, + LN2 ----
    #pragma unroll
    for (int r = 0; r < 4; r++) {
        int rw = 4*g16 + r;
        int row = rbase + rw;
        float bm = __shfl(mean, rw);              // stats live in lanes 0..15
        float br = __shfl(rstd, rw);
        int imr2 = __shfl(imr, rw);
        float tmp[8];
        float s2 = 0.f, q2 = 0.f;
        #pragma unroll
        for (int tn = 0; tn < 8; tn++) {
            int col = 16*tn + l15;
            float xr = src[(size_t)row * DM + col];
            if (imr2 >= 0) xr = xr + (float)Ob[(size_t)imr2 * DM + col];
            float y  = (xr - bm) * br * g1[col] + b1ln[col];
            float v  = o[tn][r] + fb2[col] + y;
            tmp[tn] = v; s2 += v; q2 += v * v;
        }
        #pragma unroll
        for (int d = 1; d <= 8; d <<= 1) { s2 += __shfl_xor(s2, d); q2 += __shfl_xor(q2, d); }
        float mean2 = s2 * (1.f/128.f);
        float var2  = q2 * (1.f/128.f) - mean2 * mean2;
        float rstd2 = rsqrtf(var2 + 1e-5f);
        #pragma unroll
        for (int tn = 0; tn < 8; tn++) {
            int col = 16*tn + l15;
            out[(size_t)row * DM + col] = (tmp[tn] - mean2) * rstd2 * g2[col] + b2ln[col];
        }
    }
}

// ---------------- launcher ----------------
extern "C" void kernel_launch(void* const* d_in, const int* in_sizes, int n_in,
                              void* d_out, int out_size, void* d_ws, size_t ws_size,
                              hipStream_t stream)
{
    const float* src      = (const float*)d_in[0];
    const float* src_prv  = (const float*)d_in[1];
    const float* pos      = (const float*)d_in[2];
    const float* pos_prv  = (const float*)d_in[3];
    const float* inpw     = (const float*)d_in[4];
    const float* inpb     = (const float*)d_in[5];
    const float* outpw    = (const float*)d_in[6];
    const float* outpb    = (const float*)d_in[7];
    const float* l1w      = (const float*)d_in[8];
    const float* l1b      = (const float*)d_in[9];
    const float* l2w      = (const float*)d_in[10];
    const float* l2b      = (const float*)d_in[11];
    const float* ln1g     = (const float*)d_in[12];
    const float* ln1b     = (const float*)d_in[13];
    const float* ln2g     = (const float*)d_in[14];
    const float* ln2b     = (const float*)d_in[15];
    const int* keep       = (const int*)d_in[16];
    const int* keep_p     = (const int*)d_in[17];
    const int* inds       = (const int*)d_in[18];
    const int* inds_p     = (const int*)d_in[19];
    const int n_inds = in_sizes[18], n_prv = in_sizes[19];

    char* wsb = (char*)d_ws;
    bf16* whi  = (bf16*)(wsb);                                  // 262144 B
    int*  mq   = (int*)(wsb + 524288);                          // 524288 B
    int*  mkv  = (int*)(wsb + 1048576);                         // 524288 B
    int*  im   = (int*)(wsb + 1572864);                         // 524288 B
    bf16* Qb   = (bf16*)(wsb + 2097152);                        // 33554432 B
    bf16* Kb   = (bf16*)(wsb + 2097152 + 1u*33554432);          // 33554432 B
    bf16* Vtb  = (bf16*)(wsb + 2097152 + 2u*33554432);          // 33554432 B
    bf16* Ob   = (bf16*)(wsb + 2097152 + 3u*33554432);          // 33554432 B
    unsigned char* kmask = (unsigned char*)(wsb + 2097152 + 4u*33554432);  // 131072 B
    int* mflag = (int*)(wsb + 2097152 + 4u*33554432 + 131072);  // 4 B

    int mmax = n_inds > n_prv ? n_inds : n_prv;
    if (mmax < 32768) mmax = 32768;
    k_prep1<<<512, 256, 0, stream>>>(inpw, outpw, l1w, l2w, whi, mq, mkv, im, mflag);
    k_prep2<<<(mmax + 255) / 256, 256, 0, stream>>>((const int*)d_in[20], mflag,
                                                    inds, keep, n_inds, inds_p, keep_p, n_prv, mq, mkv, im);
    k_prep3<<<512, 256, 0, stream>>>((const int*)d_in[20], (const unsigned char*)d_in[20], mflag, kmask);
    k_qkv<<<dim3(2048, 2), 256, 0, stream>>>(src, src_prv, pos, pos_prv, whi, inpb, mq, mkv, Qb, Kb, Vtb);
    k_attn<<<NWIN, 256, 0, stream>>>(Qb, Kb, Vtb, whi, outpb, kmask, Ob);
    k_ffn<<<NTOT / 64, 256, 0, stream>>>(src, Ob, im, whi, ln1g, ln1b, l1b, l2b, ln2g, ln2b, (float*)d_out);
}